// Round 1
// baseline (96.464 us; speedup 1.0000x reference)
//
#include <hip/hip_runtime.h>
#include <hip/hip_bf16.h>
#include <stdint.h>

typedef short short8 __attribute__((ext_vector_type(8)));
typedef float f32x4 __attribute__((ext_vector_type(4)));
typedef unsigned short ushort4v __attribute__((ext_vector_type(4)));

#define MDIM 8192
#define KDIM 1024
#define NDIM 1024

#define BM 128
#define BN 64
#define BK 64
#define NKSTEP (KDIM / BK) // 16

// ---------- helpers ----------

__device__ __forceinline__ unsigned short f2bf(float f) {
  union { float f; unsigned int u; } v; v.f = f;
  unsigned int u = v.u;
  u += 0x7fffu + ((u >> 16) & 1u);   // round-to-nearest-even
  return (unsigned short)(u >> 16);
}

__device__ __forceinline__ void load_lds16(const void* gsrc, void* ldst) {
  __builtin_amdgcn_global_load_lds(
      (__attribute__((address_space(1))) void*)gsrc,
      (__attribute__((address_space(3))) void*)ldst,
      16, 0, 0);
}

__device__ __forceinline__ float fast_sigmoid(float x) {
  return 1.0f / (1.0f + __expf(-x));
}

__device__ __forceinline__ float fast_tanh(float x) {
  x = fminf(30.0f, fmaxf(-30.0f, x));
  float e = __expf(-2.0f * x);
  return (1.0f - e) / (1.0f + e);
}

// ---------- conversion kernels ----------

// hprev f32 -> bf16, row-major [M][K]
__global__ void convert_h_kernel(const float* __restrict__ in,
                                 unsigned short* __restrict__ out, int n4) {
  int idx = blockIdx.x * blockDim.x + threadIdx.x;
  int stride = gridDim.x * blockDim.x;
  for (int i = idx; i < n4; i += stride) {
    float4 v = reinterpret_cast<const float4*>(in)[i];
    ushort4v o;
    o.x = f2bf(v.x); o.y = f2bf(v.y); o.z = f2bf(v.z); o.w = f2bf(v.w);
    reinterpret_cast<ushort4v*>(out)[i] = o;
  }
}

// w[k][n] f32 -> wT[gate][n][k] bf16 (transpose, LDS-tiled 64x64)
__global__ void convert_w_kernel(const float* __restrict__ w0,
                                 const float* __restrict__ w1,
                                 const float* __restrict__ w2,
                                 const float* __restrict__ w3,
                                 unsigned short* __restrict__ wT) {
  __shared__ float tile[64][65];  // +1 pad: conflict-free transposed read
  int g = blockIdx.z;
  const float* w = (g == 0) ? w0 : (g == 1) ? w1 : (g == 2) ? w2 : w3;
  int k0 = blockIdx.y * 64;
  int n0 = blockIdx.x * 64;
  int tx = threadIdx.x;  // 0..63
  int ty = threadIdx.y;  // 0..3
#pragma unroll
  for (int j = 0; j < 16; ++j) {
    int kk = ty * 16 + j;
    tile[kk][tx] = w[(size_t)(k0 + kk) * NDIM + n0 + tx];  // coalesced read
  }
  __syncthreads();
  unsigned short* dst = wT + (size_t)g * NDIM * KDIM;
#pragma unroll
  for (int j = 0; j < 16; ++j) {
    int nn = ty * 16 + j;
    dst[(size_t)(n0 + nn) * KDIM + k0 + tx] = f2bf(tile[tx][nn]);  // coalesced write
  }
}

// ---------- fused 4-gate GEMM + LSTM epilogue ----------
//
// Block: 256 threads = 4 waves (2 row-waves x 2 col-waves).
// Tile: BM=128 rows of hprev, BN=64 gate-cols, all 4 gates at once.
// Per wave: 64x32 output per gate, mfma_f32_16x16x32_bf16, acc 4x4x2 f32x4.
// LDS (48 KB, single buffer, m97-style 2-barrier loop):
//   A:  [128 rows][128 B] bf16, XOR-swizzled (slot ^= row&7, 16B slots)
//   Bg: [4][64 rows][128 B] bf16, same swizzle.
// Staging: global_load_lds width 16; swizzle applied on the GLOBAL source
// address (LDS dest stays linear: wave-uniform base + lane*16).

__global__ __launch_bounds__(256, 2) void lstm_fused_gemm(
    const unsigned short* __restrict__ hbf,   // [M][K] bf16
    const unsigned short* __restrict__ wT,    // [4][N][K] bf16
    const float* __restrict__ cprev,          // [M][N] f32
    const float* __restrict__ b_i, const float* __restrict__ b_f,
    const float* __restrict__ b_g, const float* __restrict__ b_o,
    float* __restrict__ out)                  // [2][M][N] f32: hprime, cprime
{
  __shared__ unsigned char lds[48 * 1024];
  const int tid = threadIdx.x;
  const int lane = tid & 63;
  const int wave = tid >> 6;

  // XCD-bijective swizzle: 1024 blocks % 8 == 0, 128 per XCD chunk.
  int bid = blockIdx.x;
  int swz = (bid & 7) * 128 + (bid >> 3);
  int mb = swz >> 4;        // 0..63
  int nb = swz & 15;        // 0..15
  int brow = mb * BM;
  int bcol = nb * BN;

  const int wr = wave >> 1, wc = wave & 1;
  const int wrow = wr * 64, wcol = wc * 32;

  // Staging source byte offsets (k0 advance = +128 B per K-step).
  // A: 1024 chunks of 16 B; thread handles chunks j*256+tid (wave-contiguous).
  uint32_t offA[4], offB[8];
#pragma unroll
  for (int j = 0; j < 4; ++j) {
    int c = j * 256 + tid;
    int row = c >> 3, slot = c & 7;
    offA[j] = (uint32_t)((brow + row) * (KDIM * 2) + ((slot ^ (row & 7)) * 16));
  }
#pragma unroll
  for (int j = 0; j < 8; ++j) {
    int c = j * 256 + tid;
    int g = c >> 9;
    int row = (c >> 3) & 63;
    int slot = c & 7;
    offB[j] = (uint32_t)((g * NDIM + bcol + row) * (KDIM * 2) +
                         ((slot ^ (row & 7)) * 16));
  }

  const int h = lane >> 4;    // k-chunk group 0..3
  const int r15 = lane & 15;  // fragment row/col
  const int s = lane & 7;     // swizzle index (== row&7 for all frag rows)

  f32x4 acc[4][4][2];
#pragma unroll
  for (int g = 0; g < 4; ++g)
#pragma unroll
    for (int mf = 0; mf < 4; ++mf)
#pragma unroll
      for (int nf = 0; nf < 2; ++nf)
        acc[g][mf][nf] = (f32x4){0.f, 0.f, 0.f, 0.f};

  const char* hbase = (const char*)hbf;
  const char* wbase = (const char*)wT;

  for (int t = 0; t < NKSTEP; ++t) {
    const char* ha = hbase + t * 128;
    const char* wa = wbase + t * 128;
#pragma unroll
    for (int j = 0; j < 4; ++j)
      load_lds16(ha + offA[j], lds + tid * 16 + j * 4096);
#pragma unroll
    for (int j = 0; j < 8; ++j)
      load_lds16(wa + offB[j], lds + 16384 + tid * 16 + j * 4096);
    __syncthreads();   // compiler drains vmcnt(0) here -> LDS tile ready

#pragma unroll
    for (int kk = 0; kk < 2; ++kk) {
      short8 a[4];
#pragma unroll
      for (int mf = 0; mf < 4; ++mf) {
        int off = (wrow + mf * 16 + r15) * 128 + (((kk * 4 + h) ^ s) * 16);
        a[mf] = *reinterpret_cast<const short8*>(lds + off);
      }
#pragma unroll
      for (int g = 0; g < 4; ++g) {
#pragma unroll
        for (int nf = 0; nf < 2; ++nf) {
          int off = 16384 + g * 8192 +
                    (wcol + nf * 16 + r15) * 128 + (((kk * 4 + h) ^ s) * 16);
          short8 b = *reinterpret_cast<const short8*>(lds + off);
#pragma unroll
          for (int mf = 0; mf < 4; ++mf)
            acc[g][mf][nf] = __builtin_amdgcn_mfma_f32_16x16x32_bf16(
                a[mf], b, acc[g][mf][nf], 0, 0, 0);
        }
      }
    }
    __syncthreads();   // protect LDS before next stage overwrites
  }

  // ---- fused LSTM epilogue (all in registers / fp32) ----
  // C/D layout (m89/m91-verified): col = lane&15, row = (lane>>4)*4 + reg.
  const size_t outCstride = (size_t)MDIM * NDIM;
#pragma unroll
  for (int nf = 0; nf < 2; ++nf) {
    int cc = bcol + wcol + nf * 16 + r15;
    float bi = b_i[cc];
    float bff = b_f[cc];
    float bg = b_g[cc];
    float bo = b_o[cc];
#pragma unroll
    for (int mf = 0; mf < 4; ++mf) {
#pragma unroll
      for (int j = 0; j < 4; ++j) {
        int rr = brow + wrow + mf * 16 + h * 4 + j;
        size_t base = (size_t)rr * NDIM + cc;
        float pi = acc[0][mf][nf][j] + bi;
        float pf = acc[1][mf][nf][j] + bff;
        float pg = acc[2][mf][nf][j] + bg;
        float po = acc[3][mf][nf][j] + bo;
        float iv = fast_sigmoid(pi);
        float fv = fast_sigmoid(pf);
        float gv = fast_tanh(pg);
        float ov = fast_sigmoid(po);
        float cp = fv * cprev[base] + iv * gv;
        float hp = ov * fast_tanh(cp);
        out[base] = hp;
        out[outCstride + base] = cp;
      }
    }
  }
}

// ---------- launch ----------

extern "C" void kernel_launch(void* const* d_in, const int* in_sizes, int n_in,
                              void* d_out, int out_size, void* d_ws, size_t ws_size,
                              hipStream_t stream) {
  const float* hprev = (const float*)d_in[0];
  const float* cprev = (const float*)d_in[1];
  const float* w_hi  = (const float*)d_in[2];
  const float* b_hi  = (const float*)d_in[3];
  const float* w_hf  = (const float*)d_in[4];
  const float* b_hf  = (const float*)d_in[5];
  const float* w_hg  = (const float*)d_in[6];
  const float* b_hg  = (const float*)d_in[7];
  const float* w_ho  = (const float*)d_in[8];
  const float* b_ho  = (const float*)d_in[9];
  float* out = (float*)d_out;

  // workspace: [0,16MB) hprev bf16; [16MB,24MB) wT bf16 [4][N][K]
  unsigned short* hbf = (unsigned short*)d_ws;
  unsigned short* wT  = (unsigned short*)((char*)d_ws + (size_t)MDIM * KDIM * 2);

  convert_h_kernel<<<2048, 256, 0, stream>>>(hprev, hbf, MDIM * KDIM / 4);
  convert_w_kernel<<<dim3(16, 16, 4), dim3(64, 4, 1), 0, stream>>>(
      w_hi, w_hf, w_hg, w_ho, wT);
  lstm_fused_gemm<<<1024, 256, 0, stream>>>(hbf, wT, cprev,
                                            b_hi, b_hf, b_hg, b_ho, out);
}